// Round 4
// baseline (272.385 us; speedup 1.0000x reference)
//
#include <hip/hip_runtime.h>
#include <cstdint>
#include <cstddef>

// Problem constants
#define BATCH 8
#define CIN   512
#define COUT  512
#define RES   64
#define HW    4096      // 64*64
#define WDIM  512

typedef short bf16x8 __attribute__((ext_vector_type(8)));
typedef float f32x4  __attribute__((ext_vector_type(4)));
typedef float f32x4v __attribute__((ext_vector_type(4)));
typedef unsigned short ushort8 __attribute__((ext_vector_type(8)));

typedef const __attribute__((address_space(1))) void* gas_ptr;
typedef __attribute__((address_space(3))) void*       las_ptr;

__device__ __forceinline__ unsigned short f2bf(float f) {
    unsigned int u = __float_as_uint(f);
    u += 0x7fffu + ((u >> 16) & 1u);   // round-to-nearest-even
    return (unsigned short)(u >> 16);
}

// ---------------------------------------------------------------------------
// Kernel 1 (fully fused prep):
//  blocks 0..511  : modtrans with INLINE style. Block (b, ci_blk, hw8) first
//                   computes style[ci0..ci0+63] (8x redundant across hw8 — aw
//                   is L2-resident, ~64 MB total extra L2 reads), then
//                   transposes/modulates 8 tiles of 64x64:
//                   xs[b][hw][ci] = bf16(x[b][ci][hw] * style[b][ci])
//  blocks 512..1023: weight reorg wr[tap][co][ci] = bf16(weight[co][ci][tap])
//  block 512 also zeroes the zero-page used by conv's OOB staging.
// ---------------------------------------------------------------------------
__global__ __launch_bounds__(256) void prep_kernel(
    const float* __restrict__ x,  const float* __restrict__ w,
    const float* __restrict__ aw, const float* __restrict__ ab,
    const float* __restrict__ wt,
    unsigned short* __restrict__ xs, unsigned short* __restrict__ wr,
    unsigned short* __restrict__ zpage)
{
    __shared__ float sh[4608];   // role A: tile[64][65]=4160 + partials 256 + style 64
    const int bid = blockIdx.x;
    const int t   = threadIdx.x;

    if (bid < 512) {
        const int b   = bid & 7;
        const int ci0 = ((bid >> 3) & 7) * 64;
        const int hwb = (bid >> 6) * 512;          // 8 tiles of 64

        float* tile     = sh;                      // [64][65]
        float* partials = sh + 4160;               // [256]
        float* styleS   = sh + 4416;               // [64]

        // --- inline style: thread t handles (ci = t>>2, quarter q = t&3)
        {
            int cil = t >> 2, q = t & 3;
            const f32x4v* arow = (const f32x4v*)(aw + (size_t)(ci0 + cil) * WDIM + q * 128);
            const f32x4v* wrow = (const f32x4v*)(w + (size_t)b * WDIM + q * 128);
            float s = 0.f;
#pragma unroll
            for (int i = 0; i < 32; ++i) {
                f32x4v a = arow[i], ww = wrow[i];
                s += a.x * ww.x + a.y * ww.y + a.z * ww.z + a.w * ww.w;
            }
            partials[t] = s;
        }
        __syncthreads();
        if (t < 64)
            styleS[t] = partials[t * 4] + partials[t * 4 + 1] + partials[t * 4 + 2]
                      + partials[t * 4 + 3] + ab[ci0 + t];
        __syncthreads();

        // --- 8 transpose tiles
        int sub = t >> 6, lane = t & 63;
        int ci8 = (t & 7) * 8;
        for (int tl = 0; tl < 8; ++tl) {
            int hw0 = hwb + tl * 64;
#pragma unroll
            for (int r = 0; r < 16; ++r) {
                int ci = r * 4 + sub;
                tile[ci * 65 + lane] =
                    x[((size_t)(b * CIN + ci0 + ci)) * HW + hw0 + lane] * styleS[ci];
            }
            __syncthreads();
#pragma unroll
            for (int r = 0; r < 2; ++r) {
                int hw = r * 32 + (t >> 3);
                ushort8 v;
#pragma unroll
                for (int j = 0; j < 8; ++j) v[j] = f2bf(tile[(ci8 + j) * 65 + hw]);
                *(ushort8*)&xs[((size_t)b * HW + hw0 + hw) * CIN + ci0 + ci8] = v;
            }
            __syncthreads();
        }
    } else {
        if (bid == 512 && t < 128) zpage[t] = 0;
        int co = bid - 512;
#pragma unroll
        for (int r = 0; r < 18; ++r) sh[r * 256 + t] = wt[(size_t)co * 4608 + r * 256 + t];
        __syncthreads();
#pragma unroll
        for (int r = 0; r < 18; ++r) {
            int idx = r * 256 + t;
            int tap = idx >> 9, ci = idx & 511;
            wr[(size_t)tap * (COUT * CIN) + co * CIN + ci] = f2bf(sh[ci * 9 + tap]);
        }
    }
}

// ---------------------------------------------------------------------------
// Kernel 2: implicit-GEMM conv.
// C-tile 128(co) x 256(hw = 4 image rows), 512 threads = 8 waves, each wave
// owns a 64x64 quadrant (4x4 of 16x16x32 MFMA). Outer kh (3), inner ci (16).
// Per phase: stage A for 3 kw taps (As[3][128][32], 3 loads/thread) and the 4
// input rows h0+kh-1..h0+kh+2 into zero-padded Bs[4][66][32] (2 loads/thread);
// the 3 kw taps reuse staged B with a column shift. 48 MFMA per barrier pair,
// only 5 outstanding global_load_lds per thread at each barrier drain.
// LDS 41.5 KB; grid 512 -> 2 blocks/CU (16 waves/CU). bid%8 = batch so
// co-siblings share an XCD's L2.
// XOR swizzle (chunk j of LDS row r at slot j^((r>>1)&3)) keeps LDS reads
// conflict-free; staging permutes the per-lane GLOBAL source address.
// ---------------------------------------------------------------------------
__global__ __launch_bounds__(512) void conv_kernel(
    const unsigned short* __restrict__ xs,   // [8][4096][512] bf16
    const unsigned short* __restrict__ wr,   // [9][512][512]  bf16
    const float* __restrict__ bias,
    const unsigned short* __restrict__ zpage,
    float* __restrict__ y)                   // [8][512][4096] f32
{
    __shared__ __align__(16) unsigned short As[3 * 128 * 32];  // 24 KB
    __shared__ __align__(16) unsigned short Bs[4 * 66 * 32];   // 16.5 KB

    const int t   = threadIdx.x;
    const int bid = blockIdx.x;
    const int b   = bid & 7;
    const int h0  = ((bid >> 3) & 15) * 4;
    const int co0 = (bid >> 7) * 128;

    const int lane = t & 63;
    const int wv   = t >> 6;
    const int wm   = (wv & 1) * 64;
    const int wn   = (wv >> 1) * 64;      // 0,64,128,192
    const int r16  = lane & 15;
    const int quad = lane >> 4;

    // zero the pad columns (w'=0 and w'=65) of all 4 Bs rows
    if (t < 256) {
        int s = t >> 6, c = t & 63;
        int col = (c < 32) ? 0 : 65;
        Bs[(s * 66 + col) * 32 + (c & 31)] = 0;
    }

    f32x4 acc[4][4];
#pragma unroll
    for (int mi = 0; mi < 4; ++mi)
#pragma unroll
        for (int ni = 0; ni < 4; ++ni)
            acc[mi][ni] = (f32x4){0.f, 0.f, 0.f, 0.f};

    for (int kh = 0; kh < 3; ++kh) {
        // A staging: 3 x 16B per thread = As[3 taps][128 co][32 ci], swizzled
        const unsigned short* pA[3];
#pragma unroll
        for (int L = 0; L < 3; ++L) {
            int lin = L * 512 + t;                 // 0..1535
            int tap = kh * 3 + (lin >> 9);
            int q   = (lin >> 2) & 127;
            int c8  = ((lin & 3) ^ ((lin >> 3) & 3)) * 8;
            pA[L] = wr + (size_t)tap * (COUT * CIN) + (co0 + q) * CIN + c8;
        }
        // B staging: 2 x 16B per thread = 4 input rows x 64 w x 32 ci, swizzled
        const unsigned short* pB[2];
        int sB[2];
#pragma unroll
        for (int L = 0; L < 2; ++L) {
            int lin = L * 512 + t;                 // 0..1023
            int s  = lin >> 8, r8 = lin & 255;
            int wc = r8 >> 2;
            int rowp = s * 66 + 1 + wc;
            int c8 = ((r8 & 3) ^ ((rowp >> 1) & 3)) * 8;
            int hp = h0 + kh - 1 + s;
            bool ok = (unsigned)hp < 64u;
            pB[L] = ok ? xs + ((size_t)b * HW + hp * 64 + wc) * CIN + c8 : zpage;
            sB[L] = ok ? 32 : 0;
        }

        for (int ch = 0; ch < 16; ++ch) {
#pragma unroll
            for (int L = 0; L < 3; ++L) {
                int lin = L * 512 + t;
                __builtin_amdgcn_global_load_lds((gas_ptr)pA[L], (las_ptr)&As[lin * 8], 16, 0, 0);
                pA[L] += 32;
            }
#pragma unroll
            for (int L = 0; L < 2; ++L) {
                int lin = L * 512 + t;
                int s = lin >> 8, r8 = lin & 255;
                __builtin_amdgcn_global_load_lds((gas_ptr)pB[L],
                    (las_ptr)&Bs[(s * 66 + 1) * 32 + r8 * 8], 16, 0, 0);
                pB[L] += sB[L];
            }
            __syncthreads();
#pragma unroll
            for (int kw = 0; kw < 3; ++kw) {
                bf16x8 af[4], bfv[4];
#pragma unroll
                for (int mi = 0; mi < 4; ++mi) {
                    int row = kw * 128 + wm + mi * 16 + r16;
                    int ck  = quad ^ ((row >> 1) & 3);
                    af[mi] = *(const bf16x8*)&As[row * 32 + ck * 8];
                }
#pragma unroll
                for (int ni = 0; ni < 4; ++ni) {
                    int n = wn + ni * 16 + r16;
                    int dh = n >> 6, wc = n & 63;
                    int row = dh * 66 + wc + kw;
                    int ck  = quad ^ ((row >> 1) & 3);
                    bfv[ni] = *(const bf16x8*)&Bs[row * 32 + ck * 8];
                }
#pragma unroll
                for (int mi = 0; mi < 4; ++mi)
#pragma unroll
                    for (int ni = 0; ni < 4; ++ni)
                        acc[mi][ni] = __builtin_amdgcn_mfma_f32_16x16x32_bf16(
                            af[mi], bfv[ni], acc[mi][ni], 0, 0, 0);
            }
            __syncthreads();
        }
    }

    // Epilogue: C/D layout col(n)=lane&15, row(m)=quad*4+reg
#pragma unroll
    for (int mi = 0; mi < 4; ++mi) {
#pragma unroll
        for (int r = 0; r < 4; ++r) {
            int m = co0 + wm + mi * 16 + quad * 4 + r;
            float bv = bias[m];
            size_t base = ((size_t)b * COUT + m) * HW + h0 * 64;
#pragma unroll
            for (int ni = 0; ni < 4; ++ni) {
                int n = wn + ni * 16 + r16;
                y[base + n] = acc[mi][ni][r] + bv;
            }
        }
    }
}

// ---------------------------------------------------------------------------
extern "C" void kernel_launch(void* const* d_in, const int* in_sizes, int n_in,
                              void* d_out, int out_size, void* d_ws, size_t ws_size,
                              hipStream_t stream)
{
    (void)in_sizes; (void)n_in; (void)out_size; (void)ws_size;
    const float* x    = (const float*)d_in[0];  // [8,512,64,64]
    const float* w    = (const float*)d_in[1];  // [8,512]
    const float* wt   = (const float*)d_in[2];  // [512,512,3,3]
    const float* bias = (const float*)d_in[3];  // [512]
    const float* aw   = (const float*)d_in[4];  // [512,512]
    const float* ab   = (const float*)d_in[5];  // [512]
    float* y = (float*)d_out;                   // [8,512,64,64]

    char* ws = (char*)d_ws;
    unsigned short* zpage = (unsigned short*)(ws + 16384);       // 256 B
    unsigned short* wr    = (unsigned short*)(ws + 32768);       // 4.5 MB
    unsigned short* xs    = (unsigned short*)(ws + 4751360);     // 32 MB

    prep_kernel<<<1024, 256, 0, stream>>>(x, w, aw, ab, wt, xs, wr, zpage);
    conv_kernel<<<512, 512, 0, stream>>>(xs, wr, bias, zpage, y);
}